// Round 5
// baseline (97.072 us; speedup 1.0000x reference)
//
#include <hip/hip_runtime.h>
#include <hip/hip_bf16.h>

// BinarizedLinear: out[d,o] = (sum_i (u_w[d,o,i] < sigmoid(w[o,i])) * x[d,i])
//                             > bias[o] + (u_b[d,o]-0.5)*0.1
// D=128, OUT=1024, IN=1024. HBM-bound on the 512 MiB u_w stream.
// Output is bool -> marshalled as int32 (write 0/1 ints).
//
// R5 changes vs R4 (92.3 us, 5.82 TB/s effective):
//  - Pre-pack x slice into 8x16-bit lane-local bitmasks BEFORE the stream.
//    The main loop is now a pure nontemporal u_w stream: no L2 x-loads
//    interleaved -> full vmcnt window used for HBM prefetch depth.

#define DD   128
#define OUTD 1024
#define IND  1024
#define D_PER_WAVE 8

typedef float floatx4 __attribute__((ext_vector_type(4)));

__global__ __launch_bounds__(256) void BinarizedLinear_41360535061123_kernel(
    const int*   __restrict__ x,     // [D][IN]   (bool as int32)
    const float* __restrict__ w,     // [OUT][IN]
    const float* __restrict__ bias,  // [OUT]
    const float* __restrict__ u_w,   // [D][OUT][IN]
    const float* __restrict__ u_b,   // [D][OUT]
    int*         __restrict__ out)   // [D][OUT]  (bool as int32 0/1)
{
    const int gtid = blockIdx.x * blockDim.x + threadIdx.x;
    const int wave = gtid >> 6;
    const int lane = threadIdx.x & 63;

    const int o  = wave & (OUTD - 1);   // o fastest: contiguous u_w rows
    const int dg = wave >> 10;
    const int d0 = dg * D_PER_WAVE;

    // Thresholds (L2-resident)
    float thr[D_PER_WAVE];
    {
        const float b = bias[o];
#pragma unroll
        for (int dd = 0; dd < D_PER_WAVE; ++dd)
            thr[dd] = b + (u_b[(size_t)(d0 + dd) * OUTD + o] - 0.5f) * 0.1f;
    }

    // p = sigmoid(w[o, i]) fragment: lane l covers i = k*256 + l*4 .. +3
    const float4* w4 = reinterpret_cast<const float4*>(w + (size_t)o * IND);
    float4 p[4];
#pragma unroll
    for (int k = 0; k < 4; ++k) {
        float4 t = w4[k * 64 + lane];
        p[k].x = 1.0f / (1.0f + __expf(-t.x));
        p[k].y = 1.0f / (1.0f + __expf(-t.y));
        p[k].z = 1.0f / (1.0f + __expf(-t.z));
        p[k].w = 1.0f / (1.0f + __expf(-t.w));
    }

    // Pre-pack x bits: mask[dd] bit (k*4+c) = x[d0+dd][k*256+lane*4+c] != 0
    unsigned mask[D_PER_WAVE];
#pragma unroll
    for (int dd = 0; dd < D_PER_WAVE; ++dd) {
        const int4* x4 = reinterpret_cast<const int4*>(
            x + (size_t)(d0 + dd) * IND);
        unsigned m = 0;
#pragma unroll
        for (int k = 0; k < 4; ++k) {
            int4 xb = x4[k * 64 + lane];
            m |= (unsigned)(xb.x != 0) << (k * 4 + 0);
            m |= (unsigned)(xb.y != 0) << (k * 4 + 1);
            m |= (unsigned)(xb.z != 0) << (k * 4 + 2);
            m |= (unsigned)(xb.w != 0) << (k * 4 + 3);
        }
        mask[dd] = m;
    }

    // Pure u_w stream
    int c[D_PER_WAVE];
#pragma unroll
    for (int dd = 0; dd < D_PER_WAVE; ++dd) c[dd] = 0;

#pragma unroll
    for (int dd = 0; dd < D_PER_WAVE; ++dd) {
        const floatx4* u4 = reinterpret_cast<const floatx4*>(
            u_w + ((size_t)(d0 + dd) * OUTD + o) * IND);
        const unsigned m = mask[dd];
#pragma unroll
        for (int k = 0; k < 4; ++k) {
            floatx4 u = __builtin_nontemporal_load(u4 + (k * 64 + lane));
            c[dd] += (int)((m >> (k * 4 + 0)) & 1u) & (u.x < p[k].x);
            c[dd] += (int)((m >> (k * 4 + 1)) & 1u) & (u.y < p[k].y);
            c[dd] += (int)((m >> (k * 4 + 2)) & 1u) & (u.z < p[k].z);
            c[dd] += (int)((m >> (k * 4 + 3)) & 1u) & (u.w < p[k].w);
        }
    }

    // Pack 2 counters per dword (fields <= 1024, no carry), butterfly once.
    int r[D_PER_WAVE / 2];
#pragma unroll
    for (int k = 0; k < D_PER_WAVE / 2; ++k)
        r[k] = c[2 * k] | (c[2 * k + 1] << 16);

#pragma unroll
    for (int k = 0; k < D_PER_WAVE / 2; ++k) {
#pragma unroll
        for (int off = 32; off >= 1; off >>= 1)
            r[k] += __shfl_down(r[k], off, 64);
    }

    if (lane == 0) {
#pragma unroll
        for (int dd = 0; dd < D_PER_WAVE; ++dd) {
            const int cc = (r[dd >> 1] >> ((dd & 1) * 16)) & 0xffff;
            out[(size_t)(d0 + dd) * OUTD + o] = ((float)cc > thr[dd]) ? 1 : 0;
        }
    }
}

extern "C" void kernel_launch(void* const* d_in, const int* in_sizes, int n_in,
                              void* d_out, int out_size, void* d_ws, size_t ws_size,
                              hipStream_t stream) {
    const int*   x    = (const int*)  d_in[0];
    const float* w    = (const float*)d_in[1];
    const float* bias = (const float*)d_in[2];
    const float* u_w  = (const float*)d_in[3];
    const float* u_b  = (const float*)d_in[4];
    int* out = (int*)d_out;

    const int n_waves  = OUTD * (DD / D_PER_WAVE);   // 16384
    const int n_blocks = n_waves / 4;                // 4096 blocks x 256 thr
    BinarizedLinear_41360535061123_kernel<<<n_blocks, 256, 0, stream>>>(
        x, w, bias, u_w, u_b, out);
}

// Round 6
// 95.414 us; speedup vs baseline: 1.0174x; 1.0174x over previous
//
#include <hip/hip_runtime.h>
#include <hip/hip_bf16.h>

// BinarizedLinear: out[d,o] = (sum_i (u_w[d,o,i] < sigmoid(w[o,i])) * x[d,i])
//                             > bias[o] + (u_b[d,o]-0.5)*0.1
// D=128, OUT=1024, IN=1024. HBM-bound on the 512 MiB u_w stream.
// Output is bool -> marshalled as int32 (write 0/1 ints).
//
// R6 = revert to R4 structure (92.3 us; R5's pre-pack regressed to 97.1) plus:
//  - threshold (u_b/bias) computation moved entirely to the lane-0 epilogue:
//    no scattered-load wait in the prologue blocking stream start.
//  - x is 0/1 int32: use xb.x directly instead of (xb.x != 0).
//  - nontemporal store for out.

#define DD   128
#define OUTD 1024
#define IND  1024
#define D_PER_WAVE 8

typedef float floatx4 __attribute__((ext_vector_type(4)));

__global__ __launch_bounds__(256) void BinarizedLinear_41360535061123_kernel(
    const int*   __restrict__ x,     // [D][IN]   (bool as int32 0/1)
    const float* __restrict__ w,     // [OUT][IN]
    const float* __restrict__ bias,  // [OUT]
    const float* __restrict__ u_w,   // [D][OUT][IN]
    const float* __restrict__ u_b,   // [D][OUT]
    int*         __restrict__ out)   // [D][OUT]  (bool as int32 0/1)
{
    const int gtid = blockIdx.x * blockDim.x + threadIdx.x;
    const int wave = gtid >> 6;
    const int lane = threadIdx.x & 63;

    const int o  = wave & (OUTD - 1);   // o fastest: contiguous u_w rows
    const int dg = wave >> 10;
    const int d0 = dg * D_PER_WAVE;

    // p = sigmoid(w[o, i]) fragment: lane l covers i = k*256 + l*4 .. +3
    const float4* w4 = reinterpret_cast<const float4*>(w + (size_t)o * IND);
    float4 p[4];
#pragma unroll
    for (int k = 0; k < 4; ++k) {
        float4 t = w4[k * 64 + lane];
        p[k].x = 1.0f / (1.0f + __expf(-t.x));
        p[k].y = 1.0f / (1.0f + __expf(-t.y));
        p[k].z = 1.0f / (1.0f + __expf(-t.z));
        p[k].w = 1.0f / (1.0f + __expf(-t.w));
    }

    int c[D_PER_WAVE];
#pragma unroll
    for (int dd = 0; dd < D_PER_WAVE; ++dd) c[dd] = 0;

#pragma unroll
    for (int dd = 0; dd < D_PER_WAVE; ++dd) {
        const int d = d0 + dd;
        const floatx4* u4 = reinterpret_cast<const floatx4*>(
            u_w + ((size_t)d * OUTD + o) * IND);
        const int4* x4 = reinterpret_cast<const int4*>(x + (size_t)d * IND);

#pragma unroll
        for (int k = 0; k < 4; ++k) {
            floatx4 u  = __builtin_nontemporal_load(u4 + (k * 64 + lane));
            int4    xb = x4[k * 64 + lane];
            c[dd] += xb.x & (u.x < p[k].x);
            c[dd] += xb.y & (u.y < p[k].y);
            c[dd] += xb.z & (u.z < p[k].z);
            c[dd] += xb.w & (u.w < p[k].w);
        }
    }

    // Pack 2 counters per dword (fields <= 1024, no carry), butterfly once.
    int r[D_PER_WAVE / 2];
#pragma unroll
    for (int k = 0; k < D_PER_WAVE / 2; ++k)
        r[k] = c[2 * k] | (c[2 * k + 1] << 16);

#pragma unroll
    for (int k = 0; k < D_PER_WAVE / 2; ++k) {
#pragma unroll
        for (int off = 32; off >= 1; off >>= 1)
            r[k] += __shfl_down(r[k], off, 64);
    }

    // Threshold + store: lane 0 only (u_b/bias are L2-resident broadcasts).
    if (lane == 0) {
        const float b = bias[o];
#pragma unroll
        for (int dd = 0; dd < D_PER_WAVE; ++dd) {
            const float thr =
                b + (u_b[(size_t)(d0 + dd) * OUTD + o] - 0.5f) * 0.1f;
            const int cc = (r[dd >> 1] >> ((dd & 1) * 16)) & 0xffff;
            __builtin_nontemporal_store(
                ((float)cc > thr) ? 1 : 0,
                out + (size_t)(d0 + dd) * OUTD + o);
        }
    }
}

extern "C" void kernel_launch(void* const* d_in, const int* in_sizes, int n_in,
                              void* d_out, int out_size, void* d_ws, size_t ws_size,
                              hipStream_t stream) {
    const int*   x    = (const int*)  d_in[0];
    const float* w    = (const float*)d_in[1];
    const float* bias = (const float*)d_in[2];
    const float* u_w  = (const float*)d_in[3];
    const float* u_b  = (const float*)d_in[4];
    int* out = (int*)d_out;

    const int n_waves  = OUTD * (DD / D_PER_WAVE);   // 16384
    const int n_blocks = n_waves / 4;                // 4096 blocks x 256 thr
    BinarizedLinear_41360535061123_kernel<<<n_blocks, 256, 0, stream>>>(
        x, w, bias, u_w, u_b, out);
}

// Round 7
// 92.473 us; speedup vs baseline: 1.0497x; 1.0318x over previous
//
#include <hip/hip_runtime.h>
#include <hip/hip_bf16.h>

// BinarizedLinear: out[d,o] = (sum_i (u_w[d,o,i] < sigmoid(w[o,i])) * x[d,i])
//                             > bias[o] + (u_b[d,o]-0.5)*0.1
// D=128, OUT=1024, IN=1024. HBM-bound on the 512 MiB u_w stream.
// Output is bool -> marshalled as int32 (write 0/1 ints).
//
// R7 = exact revert to R4 (measured best: 92.3 us = 5.82 TB/s effective,
// 92.5% of the 6.29 TB/s read-stream ceiling). R5 (x pre-pack, 97.1) and
// R6 (epilogue-thr + nt-store, 95.4) both regressed vs this base.

#define DD   128
#define OUTD 1024
#define IND  1024
#define D_PER_WAVE 8

typedef float floatx4 __attribute__((ext_vector_type(4)));

__global__ __launch_bounds__(256) void BinarizedLinear_41360535061123_kernel(
    const int*   __restrict__ x,     // [D][IN]   (bool as int32)
    const float* __restrict__ w,     // [OUT][IN]
    const float* __restrict__ bias,  // [OUT]
    const float* __restrict__ u_w,   // [D][OUT][IN]
    const float* __restrict__ u_b,   // [D][OUT]
    int*         __restrict__ out)   // [D][OUT]  (bool as int32 0/1)
{
    const int gtid = blockIdx.x * blockDim.x + threadIdx.x;
    const int wave = gtid >> 6;
    const int lane = threadIdx.x & 63;

    const int o  = wave & (OUTD - 1);   // o fastest: contiguous u_w rows
    const int dg = wave >> 10;
    const int d0 = dg * D_PER_WAVE;

    // Prefetch thresholds (L2-resident; overlap latency with sigmoid calc)
    float thr[D_PER_WAVE];
    {
        const float b = bias[o];
#pragma unroll
        for (int dd = 0; dd < D_PER_WAVE; ++dd)
            thr[dd] = b + (u_b[(size_t)(d0 + dd) * OUTD + o] - 0.5f) * 0.1f;
    }

    // p = sigmoid(w[o, i]) fragment: lane l covers i = k*256 + l*4 .. +3
    const float4* w4 = reinterpret_cast<const float4*>(w + (size_t)o * IND);
    float4 p[4];
#pragma unroll
    for (int k = 0; k < 4; ++k) {
        float4 t = w4[k * 64 + lane];
        p[k].x = 1.0f / (1.0f + __expf(-t.x));
        p[k].y = 1.0f / (1.0f + __expf(-t.y));
        p[k].z = 1.0f / (1.0f + __expf(-t.z));
        p[k].w = 1.0f / (1.0f + __expf(-t.w));
    }

    int c[D_PER_WAVE];
#pragma unroll
    for (int dd = 0; dd < D_PER_WAVE; ++dd) c[dd] = 0;

#pragma unroll
    for (int dd = 0; dd < D_PER_WAVE; ++dd) {
        const int d = d0 + dd;
        const floatx4* u4 = reinterpret_cast<const floatx4*>(
            u_w + ((size_t)d * OUTD + o) * IND);
        const int4* x4 = reinterpret_cast<const int4*>(x + (size_t)d * IND);

#pragma unroll
        for (int k = 0; k < 4; ++k) {
            floatx4 u  = __builtin_nontemporal_load(u4 + (k * 64 + lane));
            int4    xb = x4[k * 64 + lane];
            c[dd] += (xb.x != 0) & (u.x < p[k].x);
            c[dd] += (xb.y != 0) & (u.y < p[k].y);
            c[dd] += (xb.z != 0) & (u.z < p[k].z);
            c[dd] += (xb.w != 0) & (u.w < p[k].w);
        }
    }

    // Pack 2 counters per dword (fields <= 1024, no carry), butterfly once.
    int r[D_PER_WAVE / 2];
#pragma unroll
    for (int k = 0; k < D_PER_WAVE / 2; ++k)
        r[k] = c[2 * k] | (c[2 * k + 1] << 16);

#pragma unroll
    for (int k = 0; k < D_PER_WAVE / 2; ++k) {
#pragma unroll
        for (int off = 32; off >= 1; off >>= 1)
            r[k] += __shfl_down(r[k], off, 64);
    }

    if (lane == 0) {
#pragma unroll
        for (int dd = 0; dd < D_PER_WAVE; ++dd) {
            const int cc = (r[dd >> 1] >> ((dd & 1) * 16)) & 0xffff;
            out[(size_t)(d0 + dd) * OUTD + o] = ((float)cc > thr[dd]) ? 1 : 0;
        }
    }
}

extern "C" void kernel_launch(void* const* d_in, const int* in_sizes, int n_in,
                              void* d_out, int out_size, void* d_ws, size_t ws_size,
                              hipStream_t stream) {
    const int*   x    = (const int*)  d_in[0];
    const float* w    = (const float*)d_in[1];
    const float* bias = (const float*)d_in[2];
    const float* u_w  = (const float*)d_in[3];
    const float* u_b  = (const float*)d_in[4];
    int* out = (int*)d_out;

    const int n_waves  = OUTD * (DD / D_PER_WAVE);   // 16384
    const int n_blocks = n_waves / 4;                // 4096 blocks x 256 thr
    BinarizedLinear_41360535061123_kernel<<<n_blocks, 256, 0, stream>>>(
        x, w, bias, u_w, u_b, out);
}